// Round 10
// baseline (428.951 us; speedup 1.0000x reference)
//
#include <hip/hip_runtime.h>

#define BS_TOK 16384
#define HD 512
#define IDIM 2048
#define NE 8
#define RT256 136             // max 256-row tiles after per-expert padding
#define RT128 272             // same space in 128-row tiles (GEMM2)
#define CAP (RT256 * 256)     // 34816 slots

typedef unsigned short u16;
typedef unsigned int u32;
typedef __attribute__((ext_vector_type(8))) __bf16 bf16x8;
typedef __attribute__((ext_vector_type(4))) float f32x4;

__device__ __forceinline__ u16 f2bf(float f) {
  u32 u = __builtin_bit_cast(u32, f);
  u += 0x7fffu + ((u >> 16) & 1u);
  return (u16)(u >> 16);
}
__device__ __forceinline__ u16 f2bf_hw(float f) {
  u32 r;
  asm("v_cvt_pk_bf16_f32 %0, %1, %2" : "=v"(r) : "v"(f), "v"(f));
  return (u16)r;
}
__device__ __forceinline__ float bflo(u32 u) { return __builtin_bit_cast(float, u << 16); }
// gelu tanh-approx via sigmoid; exp via v_exp_f32 (=2^x), log2e folded. Saturation-safe.
__device__ __forceinline__ float gelu_t(float v) {
  float t = v * (-2.302558f - 0.1029474f * v * v);
  return v * __builtin_amdgcn_rcpf(1.0f + __builtin_amdgcn_exp2f(t));
}
__device__ __forceinline__ void gload16(const u16* g, u16* l) {
  __builtin_amdgcn_global_load_lds((const __attribute__((address_space(1))) u16*)g,
                                   (__attribute__((address_space(3))) u16*)l, 16, 0, 0);
}

// Merged weight transpose (W1 and W2 -> K-major bf16)
__global__ void k_transpose2(const float* __restrict__ W1, u16* __restrict__ W1T,
                             const float* __restrict__ W2, u16* __restrict__ W2T) {
  __shared__ float t[32][33];
  int z = blockIdx.z;
  const float* in; u16* out; int R, C, bx, by;
  if (z < NE) { in = W1; out = W1T; R = HD; C = IDIM; bx = blockIdx.x; by = blockIdx.y; }
  else { in = W2; out = W2T; R = IDIM; C = HD; bx = blockIdx.y; by = blockIdx.x; z -= NE; }
  size_t eb = (size_t)z * HD * IDIM;
  int c0 = bx * 32, r0 = by * 32;
  int tx = threadIdx.x, ty = threadIdx.y;
  #pragma unroll
  for (int j = ty; j < 32; j += 8) t[j][tx] = in[eb + (size_t)(r0 + j) * C + (c0 + tx)];
  __syncthreads();
  #pragma unroll
  for (int j = ty; j < 32; j += 8) out[eb + (size_t)(c0 + j) * R + (r0 + tx)] = f2bf_hw(t[tx][j]);
}

__global__ void k_router(const float* __restrict__ x, const float* __restrict__ Wg,
                         const float* __restrict__ bg, int* __restrict__ top_e,
                         float* __restrict__ top_w, u32* __restrict__ counts,
                         float* __restrict__ Psum, u16* __restrict__ xb) {
  __shared__ float wg_s[HD * NE];
  __shared__ float Pp[NE];
  __shared__ u32 cnt[NE];
  int tid = threadIdx.x;
  if (tid < NE) { Pp[tid] = 0.f; cnt[tid] = 0; }
  for (int i = tid; i < HD * NE; i += 256) wg_s[i] = Wg[i];
  __syncthreads();
  int wv = tid >> 6, lane = tid & 63;
  int t = blockIdx.x * 4 + wv;
  const float4* xr = (const float4*)(x + (size_t)t * HD + lane * 8);
  float4 a = xr[0], b = xr[1];
  u32 p0 = f2bf(a.x) | ((u32)f2bf(a.y) << 16);
  u32 p1 = f2bf(a.z) | ((u32)f2bf(a.w) << 16);
  u32 p2 = f2bf(b.x) | ((u32)f2bf(b.y) << 16);
  u32 p3 = f2bf(b.z) | ((u32)f2bf(b.w) << 16);
  ((uint4*)(xb + (size_t)t * HD))[lane] = make_uint4(p0, p1, p2, p3);

  float acc[NE];
  #pragma unroll
  for (int e = 0; e < NE; ++e) acc[e] = 0.f;
  #pragma unroll
  for (int j = 0; j < 8; ++j) {
    float xv = j < 4 ? (&a.x)[j] : (&b.x)[j - 4];
    int h = lane * 8 + j;
    #pragma unroll
    for (int e = 0; e < NE; ++e) acc[e] += xv * wg_s[h * NE + e];
  }
  #pragma unroll
  for (int off = 32; off > 0; off >>= 1) {
    #pragma unroll
    for (int e = 0; e < NE; ++e) acc[e] += __shfl_down(acc[e], off);
  }
  if (lane == 0) {
    float lg[NE];
    #pragma unroll
    for (int e = 0; e < NE; ++e) lg[e] = acc[e] + bg[e];
    int i1 = 0; float m1 = lg[0];
    #pragma unroll
    for (int e = 1; e < NE; ++e) if (lg[e] > m1) { m1 = lg[e]; i1 = e; }
    int i2 = -1; float m2 = -1e30f;
    #pragma unroll
    for (int e = 0; e < NE; ++e) if (e != i1 && lg[e] > m2) { m2 = lg[e]; i2 = e; }
    float s = 0.f, p[NE];
    #pragma unroll
    for (int e = 0; e < NE; ++e) { p[e] = __expf(lg[e] - m1); s += p[e]; }
    float inv = 1.f / s;
    #pragma unroll
    for (int e = 0; e < NE; ++e) { p[e] *= inv; atomicAdd(&Pp[e], p[e]); }
    float denom = p[i1] + p[i2];
    top_e[2 * t] = i1; top_e[2 * t + 1] = i2;
    top_w[2 * t] = p[i1] / denom; top_w[2 * t + 1] = p[i2] / denom;
    atomicAdd(&cnt[i1], 1u); atomicAdd(&cnt[i2], 1u);
  }
  __syncthreads();
  if (tid < NE) { atomicAdd(&counts[tid], cnt[tid]); atomicAdd(&Psum[tid], Pp[tid]); }
}

// scatter with fused scan: every block derives padoff locally from counts;
// block 0 also publishes padoff[] and the balance loss.
__global__ void k_scatter(const int* __restrict__ top_e, const float* __restrict__ top_w,
                          const u32* __restrict__ counts, const float* __restrict__ Psum,
                          u32* __restrict__ pos_rel, int* __restrict__ perm_t,
                          float* __restrict__ perm_w, u32* __restrict__ padoff,
                          float* __restrict__ out) {
  __shared__ u32 po[NE];
  if (threadIdx.x == 0) {
    u32 off = 0; float loss = 0.f;
    for (int e = 0; e < NE; ++e) {
      po[e] = off;
      off += ((counts[e] + 255u) / 256u) * 256u;
      loss += ((float)counts[e] / (float)(BS_TOK * 2)) * (Psum[e] / (float)BS_TOK);
    }
    if (blockIdx.x == 0) {
      for (int e = 0; e < NE; ++e) padoff[e] = po[e];
      padoff[NE] = off;
      out[(size_t)BS_TOK * HD] = 0.01f * (float)NE * loss;
    }
  }
  __syncthreads();
  int g = blockIdx.x * 256 + threadIdx.x;  // 32768 (token,k) pairs
  int e = top_e[g]; float wgt = top_w[g];
  int lane = threadIdx.x & 63;
  #pragma unroll
  for (int ee = 0; ee < NE; ++ee) {
    unsigned long long m = __ballot(e == ee);
    if (e == ee) {
      int nb = __popcll(m & ((1ull << lane) - 1ull));
      int leader = __ffsll((unsigned long long)m) - 1;
      u32 base = 0;
      if (lane == leader) base = atomicAdd(&pos_rel[ee], (u32)__popcll(m));
      base = __shfl(base, leader);
      int slot = (int)(po[ee] + base) + nb;
      perm_t[slot] = g >> 1;
      perm_w[slot] = wgt;
    }
  }
}

__global__ void k_outinit(const float* __restrict__ x, float* __restrict__ out) {
  size_t i = (size_t)blockIdx.x * 256 + threadIdx.x;
  ((float4*)out)[i] = ((const float4*)x)[i];
}

// GEMM1: 256x256 / BK=64, 512thr/8waves (2Mx4N, wave tile 128x64),
// counted-vmcnt 2-buffer pipeline, gathered A, gelu+bias epilogue -> h bf16.
__global__ __launch_bounds__(512, 2) void k_gemm1(
    const u16* __restrict__ xb, const u16* __restrict__ W1T,
    const float* __restrict__ b1, const int* __restrict__ perm_t,
    const u32* __restrict__ padoff, u16* __restrict__ h) {
  __shared__ u16 As[2][16384], Bs[2][16384];   // 128 KB
  int nb = gridDim.x;                           // 1088
  int b = blockIdx.x;
  int tile = (b & 7) * (nb >> 3) + (b >> 3);    // XCD-chunked
  int rt = tile >> 3, ct = tile & 7;            // NCT=8
  u32 s0 = (u32)rt * 256u;
  if (s0 >= padoff[NE]) return;
  int e = 0;
  #pragma unroll
  for (int k = 1; k < NE; ++k) e += (s0 >= padoff[k]) ? 1 : 0;

  int tid = threadIdx.x;                        // 0..511
  int wv = tid >> 6, lane = tid & 63;
  int l15 = lane & 15, lg4 = lane >> 4;
  int wm = wv >> 2, wn = wv & 3;

  // staging: 4 A-loads + 4 B-loads per thread; L = tid + i*512; row = L>>3
  int cb = (tid & 7) * 16;
  const u16* ap[4]; const u16* bp[4];
  #pragma unroll
  for (int i = 0; i < 4; ++i) {
    int row = (tid >> 3) + i * 64;
    int off = (cb ^ ((row & 7) << 4)) >> 1;     // pre-swizzled elem offset
    ap[i] = xb + (size_t)perm_t[s0 + row] * HD + off;
    bp[i] = W1T + ((size_t)e * IDIM + ct * 256 + row) * HD + off;
  }

  int base_n = ct * 256 + wn * 64;
  f32x4 acc[8][4];
  #pragma unroll
  for (int fc = 0; fc < 4; ++fc) {
    float bv = b1[(size_t)e * IDIM + base_n + fc * 16 + l15];
    #pragma unroll
    for (int fr = 0; fr < 8; ++fr) acc[fr][fc] = f32x4{bv, bv, bv, bv};
  }

  // prologue: stage K-steps 0,1 (16 loads in flight)
  #pragma unroll
  for (int i = 0; i < 4; ++i) gload16(ap[i], As[0] + tid * 8 + i * 4096);
  #pragma unroll
  for (int i = 0; i < 4; ++i) gload16(bp[i], Bs[0] + tid * 8 + i * 4096);
  #pragma unroll
  for (int i = 0; i < 4; ++i) gload16(ap[i] + 64, As[1] + tid * 8 + i * 4096);
  #pragma unroll
  for (int i = 0; i < 4; ++i) gload16(bp[i] + 64, Bs[1] + tid * 8 + i * 4096);
  asm volatile("s_waitcnt vmcnt(8)" ::: "memory");
  __builtin_amdgcn_sched_barrier(0);
  __builtin_amdgcn_s_barrier();

  for (int ks = 0; ks < 8; ++ks) {
    int cur = ks & 1;
    const u16* Ab = As[cur];
    const u16* Bb = Bs[cur];
    bf16x8 af[2][8], bf[2][4];
    #pragma unroll
    for (int kk = 0; kk < 2; ++kk) {
      #pragma unroll
      for (int fr = 0; fr < 8; ++fr) {
        int ra = wm * 128 + fr * 16 + l15;
        af[kk][fr] = *(const bf16x8*)((const char*)Ab +
                     (ra * 128 + ((kk * 64 + lg4 * 16) ^ ((ra & 7) << 4))));
      }
      #pragma unroll
      for (int fc = 0; fc < 4; ++fc) {
        int rb = wn * 64 + fc * 16 + l15;
        bf[kk][fc] = *(const bf16x8*)((const char*)Bb +
                     (rb * 128 + ((kk * 64 + lg4 * 16) ^ ((rb & 7) << 4))));
      }
    }
    asm volatile("s_waitcnt lgkmcnt(0)" ::: "memory");
    __builtin_amdgcn_sched_barrier(0);
    __builtin_amdgcn_s_barrier();

    if (ks + 2 < 8) {
      int k0 = (ks + 2) * 64;
      #pragma unroll
      for (int i = 0; i < 4; ++i) gload16(ap[i] + k0, As[cur] + tid * 8 + i * 4096);
      #pragma unroll
      for (int i = 0; i < 4; ++i) gload16(bp[i] + k0, Bs[cur] + tid * 8 + i * 4096);
    }

    __builtin_amdgcn_s_setprio(1);
    #pragma unroll
    for (int kk = 0; kk < 2; ++kk)
      #pragma unroll
      for (int fr = 0; fr < 8; ++fr)
        #pragma unroll
        for (int fc = 0; fc < 4; ++fc)
          acc[fr][fc] = __builtin_amdgcn_mfma_f32_16x16x32_bf16(af[kk][fr], bf[kk][fc], acc[fr][fc], 0, 0, 0);
    __builtin_amdgcn_s_setprio(0);

    if (ks + 1 < 8) {
      if (ks + 2 < 8) {
        asm volatile("s_waitcnt vmcnt(8)" ::: "memory");
      } else {
        asm volatile("s_waitcnt vmcnt(0)" ::: "memory");
      }
      __builtin_amdgcn_sched_barrier(0);
      __builtin_amdgcn_s_barrier();
    }
  }

  #pragma unroll
  for (int fr = 0; fr < 8; ++fr) {
    u32 mrow = s0 + wm * 128 + fr * 16 + lg4 * 4;
    #pragma unroll
    for (int rr = 0; rr < 4; ++rr) {
      #pragma unroll
      for (int fc = 0; fc < 4; ++fc) {
        float v = gelu_t(acc[fr][fc][rr]);
        h[(size_t)(mrow + rr) * IDIM + base_n + fc * 16 + l15] = f2bf_hw(v);
      }
    }
  }
}

// GEMM2: 128x128 / BK=64 counted-vmcnt pipeline, A=h, atomic-weighted into out.
__global__ __launch_bounds__(256, 2) void k_gemm2(
    const u16* __restrict__ h, const u16* __restrict__ W2T,
    const float* __restrict__ b2, const int* __restrict__ perm_t,
    const float* __restrict__ perm_w, const u32* __restrict__ padoff,
    float* __restrict__ out) {
  __shared__ u16 As[2][8192], Bs[2][8192];
  int nb = gridDim.x;                           // 1088
  int b = blockIdx.x;
  int tile = (b & 7) * (nb >> 3) + (b >> 3);
  int rt = tile >> 2, ct = tile & 3;            // NCT=4
  u32 s0 = (u32)rt * 128u;
  if (s0 >= padoff[NE]) return;
  int e = 0;
  #pragma unroll
  for (int k = 1; k < NE; ++k) e += (s0 >= padoff[k]) ? 1 : 0;

  int tid = threadIdx.x;
  int wv = tid >> 6, lane = tid & 63;
  int l15 = lane & 15, lg4 = lane >> 4;
  int wr = wv >> 1, wc = wv & 1;

  int srow = tid >> 3;
  int cb = (tid & 7) * 16;
  int cbs = (cb ^ ((srow & 7) << 4)) >> 1;

  const u16* ap[4]; const u16* bp[4];
  #pragma unroll
  for (int i = 0; i < 4; ++i) {
    int r = i * 32 + srow;
    ap[i] = h + (size_t)(s0 + r) * IDIM + cbs;
    bp[i] = W2T + ((size_t)e * HD + ct * 128 + r) * IDIM + cbs;
  }

  int base_n = ct * 128 + wc * 64;
  f32x4 acc[4][4];
  #pragma unroll
  for (int j = 0; j < 4; ++j) {
    float bv = b2[e * HD + base_n + j * 16 + l15];
    #pragma unroll
    for (int i = 0; i < 4; ++i) acc[i][j] = f32x4{bv, bv, bv, bv};
  }

  #pragma unroll
  for (int i = 0; i < 4; ++i) gload16(ap[i], As[0] + tid * 8 + i * 2048);
  #pragma unroll
  for (int i = 0; i < 4; ++i) gload16(bp[i], Bs[0] + tid * 8 + i * 2048);
  #pragma unroll
  for (int i = 0; i < 4; ++i) gload16(ap[i] + 64, As[1] + tid * 8 + i * 2048);
  #pragma unroll
  for (int i = 0; i < 4; ++i) gload16(bp[i] + 64, Bs[1] + tid * 8 + i * 2048);
  asm volatile("s_waitcnt vmcnt(8)" ::: "memory");
  __builtin_amdgcn_sched_barrier(0);
  __builtin_amdgcn_s_barrier();

  for (int ks = 0; ks < 32; ++ks) {
    int cur = ks & 1;
    const u16* Ab = As[cur];
    const u16* Bb = Bs[cur];
    bf16x8 af[2][4], bf[2][4];
    #pragma unroll
    for (int kk = 0; kk < 2; ++kk) {
      #pragma unroll
      for (int f = 0; f < 4; ++f) {
        int ra = wr * 64 + f * 16 + l15;
        af[kk][f] = *(const bf16x8*)((const char*)Ab +
                    (ra * 128 + ((kk * 64 + lg4 * 16) ^ ((ra & 7) << 4))));
        int rb = wc * 64 + f * 16 + l15;
        bf[kk][f] = *(const bf16x8*)((const char*)Bb +
                    (rb * 128 + ((kk * 64 + lg4 * 16) ^ ((rb & 7) << 4))));
      }
    }
    asm volatile("s_waitcnt lgkmcnt(0)" ::: "memory");
    __builtin_amdgcn_sched_barrier(0);
    __builtin_amdgcn_s_barrier();

    if (ks + 2 < 32) {
      int k0 = (ks + 2) * 64;
      #pragma unroll
      for (int i = 0; i < 4; ++i) gload16(ap[i] + k0, As[cur] + tid * 8 + i * 2048);
      #pragma unroll
      for (int i = 0; i < 4; ++i) gload16(bp[i] + k0, Bs[cur] + tid * 8 + i * 2048);
    }

    __builtin_amdgcn_s_setprio(1);
    #pragma unroll
    for (int kk = 0; kk < 2; ++kk)
      #pragma unroll
      for (int i = 0; i < 4; ++i)
        #pragma unroll
        for (int j = 0; j < 4; ++j)
          acc[i][j] = __builtin_amdgcn_mfma_f32_16x16x32_bf16(af[kk][i], bf[kk][j], acc[i][j], 0, 0, 0);
    __builtin_amdgcn_s_setprio(0);

    if (ks + 1 < 32) {
      if (ks + 2 < 32) {
        asm volatile("s_waitcnt vmcnt(8)" ::: "memory");
      } else {
        asm volatile("s_waitcnt vmcnt(0)" ::: "memory");
      }
      __builtin_amdgcn_sched_barrier(0);
      __builtin_amdgcn_s_barrier();
    }
  }

  #pragma unroll
  for (int i = 0; i < 4; ++i) {
    u32 mrow = s0 + wr * 64 + i * 16 + lg4 * 4;
    #pragma unroll
    for (int rr = 0; rr < 4; ++rr) {
      u32 m = mrow + rr;
      int tok = perm_t[m]; float wt = perm_w[m];
      if (wt != 0.f) {
        #pragma unroll
        for (int j = 0; j < 4; ++j) {
          float v = acc[i][j][rr] * wt;   // bias folded into acc
          atomicAdd(out + (size_t)tok * HD + base_n + j * 16 + l15, v);
        }
      }
    }
  }
}

extern "C" void kernel_launch(void* const* d_in, const int* in_sizes, int n_in,
                              void* d_out, int out_size, void* d_ws, size_t ws_size,
                              hipStream_t stream) {
  const float* x  = (const float*)d_in[0];
  const float* Wg = (const float*)d_in[1];
  const float* bg = (const float*)d_in[2];
  const float* W1 = (const float*)d_in[3];
  const float* b1 = (const float*)d_in[4];
  const float* W2 = (const float*)d_in[5];
  const float* b2 = (const float*)d_in[6];
  float* out = (float*)d_out;

  char* w = (char*)d_ws;
  u32* counts   = (u32*)(w + 0);
  u32* pos_rel  = (u32*)(w + 32);
  float* Psum   = (float*)(w + 64);
  u32* padoff   = (u32*)(w + 96);                 // 9 entries
  int* top_e    = (int*)(w + 256);                // 131072 B
  float* top_w  = (float*)(w + 131328);           // 131072 B
  int* perm_t   = (int*)(w + 262400);             // 139264 B
  float* perm_w = (float*)(w + 401664);           // 139264 B
  u16* xb  = (u16*)(w + 540928);                  // 16 MB
  u16* W1T = (u16*)(w + 17318144);                // 16 MB
  u16* W2T = (u16*)(w + 34095360);                // 16 MB
  u16* h   = (u16*)(w + 50872576);                // 142.6 MB
  if (ws_size < 193478912ull) return;             // loud validation fail

  (void)hipMemsetAsync(w, 0, 540928, stream);     // counts..perm_w
  k_outinit<<<(BS_TOK * HD / 4) / 256, 256, 0, stream>>>(x, out);
  k_transpose2<<<dim3(IDIM / 32, HD / 32, 2 * NE), dim3(32, 8), 0, stream>>>(W1, W1T, W2, W2T);
  k_router<<<BS_TOK / 4, 256, 0, stream>>>(x, Wg, bg, top_e, top_w, counts, Psum, xb);
  k_scatter<<<(BS_TOK * 2) / 256, 256, 0, stream>>>(top_e, top_w, counts, Psum,
                                                    pos_rel, perm_t, perm_w, padoff, out);
  k_gemm1<<<RT256 * 8, 512, 0, stream>>>(xb, W1T, b1, perm_t, padoff, h);
  k_gemm2<<<RT128 * 4, 256, 0, stream>>>(h, W2T, b2, perm_t, perm_w, padoff, out);
}

// Round 11
// 358.985 us; speedup vs baseline: 1.1949x; 1.1949x over previous
//
#include <hip/hip_runtime.h>

#define BS_TOK 16384
#define HD 512
#define IDIM 2048
#define NE 8
#define RT_MAX 264            // max 128-row tiles after per-expert padding
#define CAP (RT_MAX * 128)    // 33792 slots

typedef unsigned short u16;
typedef unsigned int u32;
typedef __attribute__((ext_vector_type(8))) __bf16 bf16x8;
typedef __attribute__((ext_vector_type(4))) float f32x4;

__device__ __forceinline__ u16 f2bf(float f) {
  u32 u = __builtin_bit_cast(u32, f);
  u += 0x7fffu + ((u >> 16) & 1u);
  return (u16)(u >> 16);
}
__device__ __forceinline__ u16 f2bf_hw(float f) {
  u32 r;
  asm("v_cvt_pk_bf16_f32 %0, %1, %2" : "=v"(r) : "v"(f), "v"(f));
  return (u16)r;
}
__device__ __forceinline__ float bflo(u32 u) { return __builtin_bit_cast(float, u << 16); }
__device__ __forceinline__ float bfhi(u32 u) { return __builtin_bit_cast(float, u & 0xffff0000u); }
// gelu tanh-approx via sigmoid; exp via v_exp_f32 (=2^x), log2e folded. Saturation-safe.
__device__ __forceinline__ float gelu_t(float v) {
  float t = v * (-2.302558f - 0.1029474f * v * v);
  return v * __builtin_amdgcn_rcpf(1.0f + __builtin_amdgcn_exp2f(t));
}
__device__ __forceinline__ void gload16(const u16* g, u16* l) {
  __builtin_amdgcn_global_load_lds((const __attribute__((address_space(1))) u16*)g,
                                   (__attribute__((address_space(3))) u16*)l, 16, 0, 0);
}

// Fused prep: blocks [0,16384) transpose W1/W2 -> K-major bf16;
// blocks [16384, 20480) run the router (4 tokens/block).
__global__ void k_prep(const float* __restrict__ W1, u16* __restrict__ W1T,
                       const float* __restrict__ W2, u16* __restrict__ W2T,
                       const float* __restrict__ x, const float* __restrict__ Wg,
                       const float* __restrict__ bg, int* __restrict__ top_e,
                       float* __restrict__ top_w, u32* __restrict__ counts,
                       float* __restrict__ Psum, u16* __restrict__ xb) {
  int bid = blockIdx.x;
  int tid = threadIdx.x;
  if (bid < 16384) {
    __shared__ float t[32][33];
    int z = bid >> 10, rem = bid & 1023;
    int gy = rem >> 6, gx = rem & 63;          // gy 0..15, gx 0..63
    const float* in; u16* out; int R, C, bx, by;
    if (z < NE) { in = W1; out = W1T; R = HD; C = IDIM; bx = gx; by = gy; }
    else { in = W2; out = W2T; R = IDIM; C = HD; bx = gy; by = gx; z -= NE; }
    size_t eb = (size_t)z * HD * IDIM;
    int c0 = bx * 32, r0 = by * 32;
    int tx = tid & 31, ty = tid >> 5;
    #pragma unroll
    for (int j = ty; j < 32; j += 8) t[j][tx] = in[eb + (size_t)(r0 + j) * C + (c0 + tx)];
    __syncthreads();
    #pragma unroll
    for (int j = ty; j < 32; j += 8) out[eb + (size_t)(c0 + j) * R + (r0 + tx)] = f2bf_hw(t[tx][j]);
    return;
  }
  // ---- router ----
  __shared__ float wg_s[HD * NE];
  __shared__ float Pp[NE];
  __shared__ u32 cnt[NE];
  if (tid < NE) { Pp[tid] = 0.f; cnt[tid] = 0; }
  for (int i = tid; i < HD * NE; i += 256) wg_s[i] = Wg[i];
  __syncthreads();
  int wv = tid >> 6, lane = tid & 63;
  int t = (bid - 16384) * 4 + wv;
  const float4* xr = (const float4*)(x + (size_t)t * HD + lane * 8);
  float4 a = xr[0], b = xr[1];
  u32 p0 = f2bf(a.x) | ((u32)f2bf(a.y) << 16);
  u32 p1 = f2bf(a.z) | ((u32)f2bf(a.w) << 16);
  u32 p2 = f2bf(b.x) | ((u32)f2bf(b.y) << 16);
  u32 p3 = f2bf(b.z) | ((u32)f2bf(b.w) << 16);
  ((uint4*)(xb + (size_t)t * HD))[lane] = make_uint4(p0, p1, p2, p3);

  float acc[NE];
  #pragma unroll
  for (int e = 0; e < NE; ++e) acc[e] = 0.f;
  #pragma unroll
  for (int j = 0; j < 8; ++j) {
    float xv = j < 4 ? (&a.x)[j] : (&b.x)[j - 4];
    int hh = lane * 8 + j;
    #pragma unroll
    for (int e = 0; e < NE; ++e) acc[e] += xv * wg_s[hh * NE + e];
  }
  #pragma unroll
  for (int off = 32; off > 0; off >>= 1) {
    #pragma unroll
    for (int e = 0; e < NE; ++e) acc[e] += __shfl_down(acc[e], off);
  }
  if (lane == 0) {
    float lg[NE];
    #pragma unroll
    for (int e = 0; e < NE; ++e) lg[e] = acc[e] + bg[e];
    int i1 = 0; float m1 = lg[0];
    #pragma unroll
    for (int e = 1; e < NE; ++e) if (lg[e] > m1) { m1 = lg[e]; i1 = e; }
    int i2 = -1; float m2 = -1e30f;
    #pragma unroll
    for (int e = 0; e < NE; ++e) if (e != i1 && lg[e] > m2) { m2 = lg[e]; i2 = e; }
    float s = 0.f, p[NE];
    #pragma unroll
    for (int e = 0; e < NE; ++e) { p[e] = __expf(lg[e] - m1); s += p[e]; }
    float inv = 1.f / s;
    #pragma unroll
    for (int e = 0; e < NE; ++e) { p[e] *= inv; atomicAdd(&Pp[e], p[e]); }
    float denom = p[i1] + p[i2];
    top_e[2 * t] = i1; top_e[2 * t + 1] = i2;
    top_w[2 * t] = p[i1] / denom; top_w[2 * t + 1] = p[i2] / denom;
    atomicAdd(&cnt[i1], 1u); atomicAdd(&cnt[i2], 1u);
  }
  __syncthreads();
  if (tid < NE) { atomicAdd(&counts[tid], cnt[tid]); atomicAdd(&Psum[tid], Pp[tid]); }
}

// scatter with fused scan: every block derives padoff locally from counts;
// block 0 also publishes padoff[] and the balance loss scalar.
__global__ void k_scatter(const int* __restrict__ top_e, const float* __restrict__ top_w,
                          const u32* __restrict__ counts, const float* __restrict__ Psum,
                          u32* __restrict__ pos_rel, int* __restrict__ perm_t,
                          float* __restrict__ perm_w, u32* __restrict__ padoff,
                          int* __restrict__ inv, float* __restrict__ out) {
  __shared__ u32 po[NE];
  if (threadIdx.x == 0) {
    u32 off = 0; float loss = 0.f;
    for (int e = 0; e < NE; ++e) {
      po[e] = off;
      off += ((counts[e] + 127u) / 128u) * 128u;
      loss += ((float)counts[e] / (float)(BS_TOK * 2)) * (Psum[e] / (float)BS_TOK);
    }
    if (blockIdx.x == 0) {
      for (int e = 0; e < NE; ++e) padoff[e] = po[e];
      padoff[NE] = off;
      out[(size_t)BS_TOK * HD] = 0.01f * (float)NE * loss;
    }
  }
  __syncthreads();
  int g = blockIdx.x * 256 + threadIdx.x;  // 32768 (token,k) pairs
  int e = top_e[g]; float wgt = top_w[g];
  int lane = threadIdx.x & 63;
  #pragma unroll
  for (int ee = 0; ee < NE; ++ee) {
    unsigned long long m = __ballot(e == ee);
    if (e == ee) {
      int nb = __popcll(m & ((1ull << lane) - 1ull));
      int leader = __ffsll((unsigned long long)m) - 1;
      u32 base = 0;
      if (lane == leader) base = atomicAdd(&pos_rel[ee], (u32)__popcll(m));
      base = __shfl(base, leader);
      int slot = (int)(po[ee] + base) + nb;
      perm_t[slot] = g >> 1;
      perm_w[slot] = wgt;
      inv[g] = slot;
    }
  }
}

// 128x128 / BK=64 GEMM, counted-vmcnt 2-buffer pipeline (proven r9 structure).
// Bias pre-folded into accumulator init. Lean gelu + cvt_pk epilogue.
template <int KSTEPS, int NCT, int NTOT, bool GATHER, bool ACT>
__global__ __launch_bounds__(256, 2) void k_gemm(
    const u16* __restrict__ A, int lda, const u16* __restrict__ W,
    const float* __restrict__ bias, const int* __restrict__ perm_t,
    const u32* __restrict__ padoff, u16* __restrict__ C) {
  __shared__ u16 As[2][8192], Bs[2][8192];
  int nb = gridDim.x;
  int b = blockIdx.x;
  int tile = (b & 7) * (nb >> 3) + (b >> 3);   // XCD-chunked (nb % 8 == 0)
  int rt = tile / NCT, ct = tile % NCT;
  u32 s0 = (u32)rt * 128u;
  if (s0 >= padoff[NE]) return;
  int e = 0;
  #pragma unroll
  for (int k = 1; k < NE; ++k) e += (s0 >= padoff[k]) ? 1 : 0;

  int tid = threadIdx.x;
  int wv = tid >> 6, lane = tid & 63;
  int l15 = lane & 15, lg4 = lane >> 4;
  int wr = wv >> 1, wc = wv & 1;

  int srow = tid >> 3;
  int cb = (tid & 7) * 16;
  int cbs = (cb ^ ((srow & 7) << 4)) >> 1;     // pre-swizzled source elem offset

  const u16* ap[4]; const u16* bp[4];
  #pragma unroll
  for (int i = 0; i < 4; ++i) {
    int r = i * 32 + srow;
    int arow = GATHER ? perm_t[s0 + r] : (int)(s0 + r);
    ap[i] = A + (size_t)arow * lda + cbs;
    bp[i] = W + ((size_t)e * NTOT + ct * 128 + r) * (KSTEPS * 64) + cbs;
  }

  int base_n = ct * 128 + wc * 64;
  f32x4 acc[4][4];
  #pragma unroll
  for (int j = 0; j < 4; ++j) {
    float bv = bias[e * NTOT + base_n + j * 16 + l15];
    #pragma unroll
    for (int i = 0; i < 4; ++i) acc[i][j] = f32x4{bv, bv, bv, bv};
  }

  // prologue: stage K-steps 0 and 1 (16 loads in flight)
  #pragma unroll
  for (int i = 0; i < 4; ++i) gload16(ap[i], As[0] + tid * 8 + i * 2048);
  #pragma unroll
  for (int i = 0; i < 4; ++i) gload16(bp[i], Bs[0] + tid * 8 + i * 2048);
  #pragma unroll
  for (int i = 0; i < 4; ++i) gload16(ap[i] + 64, As[1] + tid * 8 + i * 2048);
  #pragma unroll
  for (int i = 0; i < 4; ++i) gload16(bp[i] + 64, Bs[1] + tid * 8 + i * 2048);
  asm volatile("s_waitcnt vmcnt(8)" ::: "memory");
  __builtin_amdgcn_sched_barrier(0);
  __builtin_amdgcn_s_barrier();

  for (int ks = 0; ks < KSTEPS; ++ks) {
    int cur = ks & 1;
    const u16* Ab = As[cur];
    const u16* Bb = Bs[cur];
    bf16x8 af[2][4], bf[2][4];
    #pragma unroll
    for (int kk = 0; kk < 2; ++kk) {
      #pragma unroll
      for (int f = 0; f < 4; ++f) {
        int ra = wr * 64 + f * 16 + l15;
        af[kk][f] = *(const bf16x8*)((const char*)Ab +
                    (ra * 128 + ((kk * 64 + lg4 * 16) ^ ((ra & 7) << 4))));
        int rb = wc * 64 + f * 16 + l15;
        bf[kk][f] = *(const bf16x8*)((const char*)Bb +
                    (rb * 128 + ((kk * 64 + lg4 * 16) ^ ((rb & 7) << 4))));
      }
    }
    asm volatile("s_waitcnt lgkmcnt(0)" ::: "memory");
    __builtin_amdgcn_sched_barrier(0);                   // rule #18 fence
    __builtin_amdgcn_s_barrier();

    if (ks + 2 < KSTEPS) {
      int k0 = (ks + 2) * 64;
      #pragma unroll
      for (int i = 0; i < 4; ++i) gload16(ap[i] + k0, As[cur] + tid * 8 + i * 2048);
      #pragma unroll
      for (int i = 0; i < 4; ++i) gload16(bp[i] + k0, Bs[cur] + tid * 8 + i * 2048);
    }

    __builtin_amdgcn_s_setprio(1);
    #pragma unroll
    for (int kk = 0; kk < 2; ++kk)
      #pragma unroll
      for (int i = 0; i < 4; ++i)
        #pragma unroll
        for (int j = 0; j < 4; ++j)
          acc[i][j] = __builtin_amdgcn_mfma_f32_16x16x32_bf16(af[kk][i], bf[kk][j], acc[i][j], 0, 0, 0);
    __builtin_amdgcn_s_setprio(0);

    if (ks + 1 < KSTEPS) {
      if (ks + 2 < KSTEPS) {
        asm volatile("s_waitcnt vmcnt(8)" ::: "memory");
      } else {
        asm volatile("s_waitcnt vmcnt(0)" ::: "memory");
      }
      __builtin_amdgcn_sched_barrier(0);
      __builtin_amdgcn_s_barrier();
    }
  }

  #pragma unroll
  for (int i = 0; i < 4; ++i) {
    u32 mrow = s0 + wr * 64 + i * 16 + lg4 * 4;
    #pragma unroll
    for (int rr = 0; rr < 4; ++rr) {
      u32 m = mrow + rr;
      #pragma unroll
      for (int j = 0; j < 4; ++j) {
        float v = acc[i][j][rr];            // bias already in acc
        if (ACT) v = gelu_t(v);
        C[(size_t)m * NTOT + base_n + j * 16 + l15] = f2bf_hw(v);
      }
    }
  }
}

__global__ void k_final(const float* __restrict__ x, const u16* __restrict__ y,
                        const int* __restrict__ inv, const float* __restrict__ top_w,
                        float* __restrict__ out) {
  int tid = threadIdx.x;
  int t = blockIdx.x * 4 + (tid >> 6);
  int lane = tid & 63;
  int s0 = inv[2 * t], s1 = inv[2 * t + 1];
  float w0 = top_w[2 * t], w1 = top_w[2 * t + 1];
  size_t xo = (size_t)t * HD + lane * 8;
  float4 a = *(const float4*)(x + xo);
  float4 b = *(const float4*)(x + xo + 4);
  uint4 ya = *(const uint4*)(y + (size_t)s0 * HD + lane * 8);
  uint4 yb = *(const uint4*)(y + (size_t)s1 * HD + lane * 8);
  float4 o0, o1;
  o0.x = a.x + w0 * bflo(ya.x) + w1 * bflo(yb.x);
  o0.y = a.y + w0 * bfhi(ya.x) + w1 * bfhi(yb.x);
  o0.z = a.z + w0 * bflo(ya.y) + w1 * bflo(yb.y);
  o0.w = a.w + w0 * bfhi(ya.y) + w1 * bfhi(yb.y);
  o1.x = b.x + w0 * bflo(ya.z) + w1 * bflo(yb.z);
  o1.y = b.y + w0 * bfhi(ya.z) + w1 * bfhi(yb.z);
  o1.z = b.z + w0 * bflo(ya.w) + w1 * bflo(yb.w);
  o1.w = b.w + w0 * bfhi(ya.w) + w1 * bfhi(yb.w);
  *(float4*)(out + xo) = o0;
  *(float4*)(out + xo + 4) = o1;
}

extern "C" void kernel_launch(void* const* d_in, const int* in_sizes, int n_in,
                              void* d_out, int out_size, void* d_ws, size_t ws_size,
                              hipStream_t stream) {
  const float* x  = (const float*)d_in[0];
  const float* Wg = (const float*)d_in[1];
  const float* bg = (const float*)d_in[2];
  const float* W1 = (const float*)d_in[3];
  const float* b1 = (const float*)d_in[4];
  const float* W2 = (const float*)d_in[5];
  const float* b2 = (const float*)d_in[6];
  float* out = (float*)d_out;

  char* w = (char*)d_ws;
  u32* counts   = (u32*)(w + 0);
  u32* pos_rel  = (u32*)(w + 32);
  float* Psum   = (float*)(w + 64);
  u32* padoff   = (u32*)(w + 96);
  int* top_e    = (int*)(w + 256);
  float* top_w  = (float*)(w + 256 + 131072);
  int* invm     = (int*)(w + 256 + 2 * 131072);
  int* perm_t   = (int*)(w + 256 + 3 * 131072);           // 135168 B
  float* perm_w = (float*)(w + 256 + 3 * 131072 + 135168);
  u16* xb  = (u16*)(w + 663808);                          // 16 MB
  u16* W1T = (u16*)(w + 17441024);                        // 16 MB
  u16* W2T = (u16*)(w + 34218240);                        // 16 MB
  u16* h   = (u16*)(w + 50995456);                        // 132 MB
  u16* y   = (u16*)(w + 189407488);                       // 33 MB
  if (ws_size < 224010496ull) return;   // loud validation fail (modeA established r2-r9)

  (void)hipMemsetAsync(w, 0, 663808, stream);   // ctrl + top/inv/perm buffers
  k_prep<<<20480, 256, 0, stream>>>(W1, W1T, W2, W2T, x, Wg, bg,
                                    top_e, top_w, counts, Psum, xb);
  k_scatter<<<(BS_TOK * 2) / 256, 256, 0, stream>>>(top_e, top_w, counts, Psum,
                                                    pos_rel, perm_t, perm_w, padoff,
                                                    invm, out);
  k_gemm<8, 16, IDIM, true, true><<<RT_MAX * 16, 256, 0, stream>>>(
      xb, HD, W1T, b1, perm_t, padoff, h);
  k_gemm<32, 4, HD, false, false><<<RT_MAX * 4, 256, 0, stream>>>(
      h, IDIM, W2T, b2, perm_t, padoff, y);
  k_final<<<BS_TOK / 4, 256, 0, stream>>>(x, y, invm, top_w, out);
}

// Round 12
// 340.854 us; speedup vs baseline: 1.2585x; 1.0532x over previous
//
#include <hip/hip_runtime.h>

#define BS_TOK 16384
#define HD 512
#define IDIM 2048
#define NE 8
#define RT_MAX 264            // max 128-row tiles after per-expert padding
#define CAP (RT_MAX * 128)    // 33792 slots

typedef unsigned short u16;
typedef unsigned int u32;
typedef unsigned long long u64;
typedef __attribute__((ext_vector_type(8))) __bf16 bf16x8;
typedef __attribute__((ext_vector_type(4))) float f32x4;

__device__ __forceinline__ u16 f2bf(float f) {
  u32 u = __builtin_bit_cast(u32, f);
  u += 0x7fffu + ((u >> 16) & 1u);
  return (u16)(u >> 16);
}
__device__ __forceinline__ u16 f2bf_hw(float f) {
  u32 r;
  asm("v_cvt_pk_bf16_f32 %0, %1, %2" : "=v"(r) : "v"(f), "v"(f));
  return (u16)r;
}
__device__ __forceinline__ u32 pack2bf(float a, float b) {  // {lo=bf(a), hi=bf(b)}
  u32 r;
  asm("v_cvt_pk_bf16_f32 %0, %1, %2" : "=v"(r) : "v"(a), "v"(b));
  return r;
}
__device__ __forceinline__ float bflo(u32 u) { return __builtin_bit_cast(float, u << 16); }
__device__ __forceinline__ float bfhi(u32 u) { return __builtin_bit_cast(float, u & 0xffff0000u); }
// gelu tanh-approx via sigmoid; exp via v_exp_f32 (=2^x), log2e folded. Saturation-safe.
__device__ __forceinline__ float gelu_t(float v) {
  float t = v * (-2.302558f - 0.1029474f * v * v);
  return v * __builtin_amdgcn_rcpf(1.0f + __builtin_amdgcn_exp2f(t));
}
__device__ __forceinline__ void gload16(const u16* g, u16* l) {
  __builtin_amdgcn_global_load_lds((const __attribute__((address_space(1))) u16*)g,
                                   (__attribute__((address_space(3))) u16*)l, 16, 0, 0);
}

// 64x64-tile transpose f32 -> bf16: blockIdx.y selects matrix/expert
// (y<8: W1 [512][2048] -> W1T; y>=8: W2 [2048][512] -> W2T).
__global__ __launch_bounds__(256) void k_transW(const float* __restrict__ W1, u16* __restrict__ W1T,
                                                const float* __restrict__ W2, u16* __restrict__ W2T) {
  __shared__ float t[64][65];   // 16.6 KB; column reads spread across banks
  int z = blockIdx.y;
  const float* in; u16* out; int Rin, Cin;
  if (z < NE) { in = W1; out = W1T; Rin = HD; Cin = IDIM; }
  else { in = W2; out = W2T; Rin = IDIM; Cin = HD; z -= NE; }
  size_t eb = (size_t)z * HD * IDIM;
  int tpr = Cin >> 6;                       // tiles per row of input
  int r0 = (blockIdx.x / tpr) << 6, c0 = (blockIdx.x % tpr) << 6;
  int tid = threadIdx.x;
  int row = tid >> 4, c4 = (tid & 15) << 2;
  #pragma unroll
  for (int i = 0; i < 4; ++i) {
    float4 v = *(const float4*)(in + eb + (size_t)(r0 + row + i * 16) * Cin + c0 + c4);
    t[row + i * 16][c4 + 0] = v.x; t[row + i * 16][c4 + 1] = v.y;
    t[row + i * 16][c4 + 2] = v.z; t[row + i * 16][c4 + 3] = v.w;
  }
  __syncthreads();
  int cc = tid >> 4, rr = (tid & 15) << 2;
  #pragma unroll
  for (int i = 0; i < 4; ++i) {
    int c = cc + i * 16;
    u32 lo = pack2bf(t[rr + 0][c], t[rr + 1][c]);
    u32 hi = pack2bf(t[rr + 2][c], t[rr + 3][c]);
    *(u32*)(out + eb + (size_t)(c0 + c) * Rin + r0 + rr)     = lo;
    *(u32*)(out + eb + (size_t)(c0 + c) * Rin + r0 + rr + 2) = hi;
  }
}

// Router: 4 tokens/block (wave per token). Padded Wg LDS [h*9+e] -> lane stride 9
// (gcd(9,32)=1) => 2-way bank access (free). Gate h-slice: h = lane + 64*j.
__global__ void k_router(const float* __restrict__ x, const float* __restrict__ Wg,
                         const float* __restrict__ bg, int* __restrict__ top_e,
                         float* __restrict__ top_w, u32* __restrict__ counts,
                         float* __restrict__ Psum, u16* __restrict__ xb) {
  __shared__ float wg_s[HD * 9];
  __shared__ float Pp[NE];
  __shared__ u32 cnt[NE];
  int tid = threadIdx.x;
  if (tid < NE) { Pp[tid] = 0.f; cnt[tid] = 0; }
  for (int i = tid; i < HD * NE; i += 256) wg_s[(i >> 3) * 9 + (i & 7)] = Wg[i];
  __syncthreads();
  int wv = tid >> 6, lane = tid & 63;
  int t = blockIdx.x * 4 + wv;

  // bf16 copy of x (vector loads; L1-shares lines with the scalar gate loads)
  const float4* xr = (const float4*)(x + (size_t)t * HD + lane * 8);
  float4 a = xr[0], b = xr[1];
  u32 p0 = pack2bf(a.x, a.y), p1 = pack2bf(a.z, a.w);
  u32 p2 = pack2bf(b.x, b.y), p3 = pack2bf(b.z, b.w);
  ((uint4*)(xb + (size_t)t * HD))[lane] = make_uint4(p0, p1, p2, p3);

  float acc[NE];
  #pragma unroll
  for (int e = 0; e < NE; ++e) acc[e] = 0.f;
  #pragma unroll
  for (int j = 0; j < 8; ++j) {
    int h = lane + 64 * j;
    float xv = x[(size_t)t * HD + h];
    const float* wrow = wg_s + h * 9;
    #pragma unroll
    for (int e = 0; e < NE; ++e) acc[e] += xv * wrow[e];
  }
  #pragma unroll
  for (int off = 32; off > 0; off >>= 1) {
    #pragma unroll
    for (int e = 0; e < NE; ++e) acc[e] += __shfl_down(acc[e], off);
  }
  if (lane == 0) {
    float lg[NE];
    #pragma unroll
    for (int e = 0; e < NE; ++e) lg[e] = acc[e] + bg[e];
    int i1 = 0; float m1 = lg[0];
    #pragma unroll
    for (int e = 1; e < NE; ++e) if (lg[e] > m1) { m1 = lg[e]; i1 = e; }
    int i2 = -1; float m2 = -1e30f;
    #pragma unroll
    for (int e = 0; e < NE; ++e) if (e != i1 && lg[e] > m2) { m2 = lg[e]; i2 = e; }
    float s = 0.f, p[NE];
    #pragma unroll
    for (int e = 0; e < NE; ++e) { p[e] = __expf(lg[e] - m1); s += p[e]; }
    float inv = 1.f / s;
    #pragma unroll
    for (int e = 0; e < NE; ++e) { p[e] *= inv; atomicAdd(&Pp[e], p[e]); }
    float denom = p[i1] + p[i2];
    top_e[2 * t] = i1; top_e[2 * t + 1] = i2;
    top_w[2 * t] = p[i1] / denom; top_w[2 * t + 1] = p[i2] / denom;
    atomicAdd(&cnt[i1], 1u); atomicAdd(&cnt[i2], 1u);
  }
  __syncthreads();
  if (tid < NE) { atomicAdd(&counts[tid], cnt[tid]); atomicAdd(&Psum[tid], Pp[tid]); }
}

// scatter with fused scan: every block derives padoff locally from counts;
// block 0 also publishes padoff[] and the balance loss scalar.
__global__ void k_scatter(const int* __restrict__ top_e, const float* __restrict__ top_w,
                          const u32* __restrict__ counts, const float* __restrict__ Psum,
                          u32* __restrict__ pos_rel, int* __restrict__ perm_t,
                          float* __restrict__ perm_w, u32* __restrict__ padoff,
                          int* __restrict__ inv, float* __restrict__ out) {
  __shared__ u32 po[NE];
  if (threadIdx.x == 0) {
    u32 off = 0; float loss = 0.f;
    for (int e = 0; e < NE; ++e) {
      po[e] = off;
      off += ((counts[e] + 127u) / 128u) * 128u;
      loss += ((float)counts[e] / (float)(BS_TOK * 2)) * (Psum[e] / (float)BS_TOK);
    }
    if (blockIdx.x == 0) {
      for (int e = 0; e < NE; ++e) padoff[e] = po[e];
      padoff[NE] = off;
      out[(size_t)BS_TOK * HD] = 0.01f * (float)NE * loss;
    }
  }
  __syncthreads();
  int g = blockIdx.x * 256 + threadIdx.x;  // 32768 (token,k) pairs
  int e = top_e[g]; float wgt = top_w[g];
  int lane = threadIdx.x & 63;
  #pragma unroll
  for (int ee = 0; ee < NE; ++ee) {
    unsigned long long m = __ballot(e == ee);
    if (e == ee) {
      int nb = __popcll(m & ((1ull << lane) - 1ull));
      int leader = __ffsll((unsigned long long)m) - 1;
      u32 base = 0;
      if (lane == leader) base = atomicAdd(&pos_rel[ee], (u32)__popcll(m));
      base = __shfl(base, leader);
      int slot = (int)(po[ee] + base) + nb;
      perm_t[slot] = g >> 1;
      perm_w[slot] = wgt;
      inv[g] = slot;
    }
  }
}

// 128x128 / BK=64 GEMM, counted-vmcnt 2-buffer pipeline (proven r9 structure).
template <int KSTEPS, int NCT, int NTOT, bool GATHER, bool ACT>
__global__ __launch_bounds__(256, 2) void k_gemm(
    const u16* __restrict__ A, int lda, const u16* __restrict__ W,
    const float* __restrict__ bias, const int* __restrict__ perm_t,
    const u32* __restrict__ padoff, u16* __restrict__ C) {
  __shared__ u16 As[2][8192], Bs[2][8192];
  int nb = gridDim.x;
  int b = blockIdx.x;
  int tile = (b & 7) * (nb >> 3) + (b >> 3);   // XCD-chunked (nb % 8 == 0)
  int rt = tile / NCT, ct = tile % NCT;
  u32 s0 = (u32)rt * 128u;
  if (s0 >= padoff[NE]) return;
  int e = 0;
  #pragma unroll
  for (int k = 1; k < NE; ++k) e += (s0 >= padoff[k]) ? 1 : 0;

  int tid = threadIdx.x;
  int wv = tid >> 6, lane = tid & 63;
  int l15 = lane & 15, lg4 = lane >> 4;
  int wr = wv >> 1, wc = wv & 1;

  int srow = tid >> 3;
  int cb = (tid & 7) * 16;
  int cbs = (cb ^ ((srow & 7) << 4)) >> 1;     // pre-swizzled source elem offset

  const u16* ap[4]; const u16* bp[4];
  #pragma unroll
  for (int i = 0; i < 4; ++i) {
    int r = i * 32 + srow;
    int arow = GATHER ? perm_t[s0 + r] : (int)(s0 + r);
    ap[i] = A + (size_t)arow * lda + cbs;
    bp[i] = W + ((size_t)e * NTOT + ct * 128 + r) * (KSTEPS * 64) + cbs;
  }

  int base_n = ct * 128 + wc * 64;
  f32x4 acc[4][4];
  #pragma unroll
  for (int j = 0; j < 4; ++j) {
    float bv = bias[e * NTOT + base_n + j * 16 + l15];
    #pragma unroll
    for (int i = 0; i < 4; ++i) acc[i][j] = f32x4{bv, bv, bv, bv};
  }

  // prologue: stage K-steps 0 and 1 (16 loads in flight)
  #pragma unroll
  for (int i = 0; i < 4; ++i) gload16(ap[i], As[0] + tid * 8 + i * 2048);
  #pragma unroll
  for (int i = 0; i < 4; ++i) gload16(bp[i], Bs[0] + tid * 8 + i * 2048);
  #pragma unroll
  for (int i = 0; i < 4; ++i) gload16(ap[i] + 64, As[1] + tid * 8 + i * 2048);
  #pragma unroll
  for (int i = 0; i < 4; ++i) gload16(bp[i] + 64, Bs[1] + tid * 8 + i * 2048);
  asm volatile("s_waitcnt vmcnt(8)" ::: "memory");
  __builtin_amdgcn_sched_barrier(0);
  __builtin_amdgcn_s_barrier();

  for (int ks = 0; ks < KSTEPS; ++ks) {
    int cur = ks & 1;
    const u16* Ab = As[cur];
    const u16* Bb = Bs[cur];
    bf16x8 af[2][4], bf[2][4];
    #pragma unroll
    for (int kk = 0; kk < 2; ++kk) {
      #pragma unroll
      for (int f = 0; f < 4; ++f) {
        int ra = wr * 64 + f * 16 + l15;
        af[kk][f] = *(const bf16x8*)((const char*)Ab +
                    (ra * 128 + ((kk * 64 + lg4 * 16) ^ ((ra & 7) << 4))));
        int rb = wc * 64 + f * 16 + l15;
        bf[kk][f] = *(const bf16x8*)((const char*)Bb +
                    (rb * 128 + ((kk * 64 + lg4 * 16) ^ ((rb & 7) << 4))));
      }
    }
    asm volatile("s_waitcnt lgkmcnt(0)" ::: "memory");
    __builtin_amdgcn_sched_barrier(0);                   // rule #18 fence
    __builtin_amdgcn_s_barrier();

    if (ks + 2 < KSTEPS) {
      int k0 = (ks + 2) * 64;
      #pragma unroll
      for (int i = 0; i < 4; ++i) gload16(ap[i] + k0, As[cur] + tid * 8 + i * 2048);
      #pragma unroll
      for (int i = 0; i < 4; ++i) gload16(bp[i] + k0, Bs[cur] + tid * 8 + i * 2048);
    }

    __builtin_amdgcn_s_setprio(1);
    #pragma unroll
    for (int kk = 0; kk < 2; ++kk)
      #pragma unroll
      for (int i = 0; i < 4; ++i)
        #pragma unroll
        for (int j = 0; j < 4; ++j)
          acc[i][j] = __builtin_amdgcn_mfma_f32_16x16x32_bf16(af[kk][i], bf[kk][j], acc[i][j], 0, 0, 0);
    __builtin_amdgcn_s_setprio(0);

    if (ks + 1 < KSTEPS) {
      if (ks + 2 < KSTEPS) {
        asm volatile("s_waitcnt vmcnt(8)" ::: "memory");
      } else {
        asm volatile("s_waitcnt vmcnt(0)" ::: "memory");
      }
      __builtin_amdgcn_sched_barrier(0);
      __builtin_amdgcn_s_barrier();
    }
  }

  #pragma unroll
  for (int i = 0; i < 4; ++i) {
    u32 mrow = s0 + wr * 64 + i * 16 + lg4 * 4;
    #pragma unroll
    for (int rr = 0; rr < 4; ++rr) {
      u32 m = mrow + rr;
      #pragma unroll
      for (int j = 0; j < 4; ++j) {
        float v = acc[i][j][rr];            // bias already in acc
        if (ACT) v = gelu_t(v);
        C[(size_t)m * NTOT + base_n + j * 16 + l15] = f2bf_hw(v);
      }
    }
  }
}

__global__ void k_final(const float* __restrict__ x, const u16* __restrict__ y,
                        const int* __restrict__ inv, const float* __restrict__ top_w,
                        float* __restrict__ out) {
  int tid = threadIdx.x;
  int t = blockIdx.x * 4 + (tid >> 6);
  int lane = tid & 63;
  int s0 = inv[2 * t], s1 = inv[2 * t + 1];
  float w0 = top_w[2 * t], w1 = top_w[2 * t + 1];
  size_t xo = (size_t)t * HD + lane * 8;
  float4 a = *(const float4*)(x + xo);
  float4 b = *(const float4*)(x + xo + 4);
  uint4 ya = *(const uint4*)(y + (size_t)s0 * HD + lane * 8);
  uint4 yb = *(const uint4*)(y + (size_t)s1 * HD + lane * 8);
  float4 o0, o1;
  o0.x = a.x + w0 * bflo(ya.x) + w1 * bflo(yb.x);
  o0.y = a.y + w0 * bfhi(ya.x) + w1 * bfhi(yb.x);
  o0.z = a.z + w0 * bflo(ya.y) + w1 * bflo(yb.y);
  o0.w = a.w + w0 * bfhi(ya.y) + w1 * bfhi(yb.y);
  o1.x = b.x + w0 * bflo(ya.z) + w1 * bflo(yb.z);
  o1.y = b.y + w0 * bfhi(ya.z) + w1 * bfhi(yb.z);
  o1.z = b.z + w0 * bflo(ya.w) + w1 * bflo(yb.w);
  o1.w = b.w + w0 * bfhi(ya.w) + w1 * bfhi(yb.w);
  *(float4*)(out + xo) = o0;
  *(float4*)(out + xo + 4) = o1;
}

extern "C" void kernel_launch(void* const* d_in, const int* in_sizes, int n_in,
                              void* d_out, int out_size, void* d_ws, size_t ws_size,
                              hipStream_t stream) {
  const float* x  = (const float*)d_in[0];
  const float* Wg = (const float*)d_in[1];
  const float* bg = (const float*)d_in[2];
  const float* W1 = (const float*)d_in[3];
  const float* b1 = (const float*)d_in[4];
  const float* W2 = (const float*)d_in[5];
  const float* b2 = (const float*)d_in[6];
  float* out = (float*)d_out;

  char* w = (char*)d_ws;
  u32* counts   = (u32*)(w + 0);
  u32* pos_rel  = (u32*)(w + 32);
  float* Psum   = (float*)(w + 64);
  u32* padoff   = (u32*)(w + 96);
  int* top_e    = (int*)(w + 256);
  float* top_w  = (float*)(w + 256 + 131072);
  int* invm     = (int*)(w + 256 + 2 * 131072);
  int* perm_t   = (int*)(w + 256 + 3 * 131072);           // 135168 B
  float* perm_w = (float*)(w + 256 + 3 * 131072 + 135168);
  u16* xb  = (u16*)(w + 663808);                          // 16 MB
  u16* W1T = (u16*)(w + 17441024);                        // 16 MB
  u16* W2T = (u16*)(w + 34218240);                        // 16 MB
  u16* h   = (u16*)(w + 50995456);                        // 132 MB
  u16* y   = (u16*)(w + 189407488);                       // 33 MB
  if (ws_size < 224010496ull) return;   // loud validation fail

  (void)hipMemsetAsync(w, 0, 663808, stream);   // ctrl + top/inv/perm buffers
  k_transW<<<dim3(256, 16), 256, 0, stream>>>(W1, W1T, W2, W2T);
  k_router<<<BS_TOK / 4, 256, 0, stream>>>(x, Wg, bg, top_e, top_w, counts, Psum, xb);
  k_scatter<<<(BS_TOK * 2) / 256, 256, 0, stream>>>(top_e, top_w, counts, Psum,
                                                    pos_rel, perm_t, perm_w, padoff,
                                                    invm, out);
  k_gemm<8, 16, IDIM, true, true><<<RT_MAX * 16, 256, 0, stream>>>(
      xb, HD, W1T, b1, perm_t, padoff, h);
  k_gemm<32, 4, HD, false, false><<<RT_MAX * 4, 256, 0, stream>>>(
      h, IDIM, W2T, b2, perm_t, padoff, y);
  k_final<<<BS_TOK / 4, 256, 0, stream>>>(x, y, invm, top_w, out);
}